// Round 4
// baseline (263.128 us; speedup 1.0000x reference)
//
#include <hip/hip_runtime.h>
#include <hip/hip_bf16.h>
#include <hip/hip_cooperative_groups.h>

namespace cg = cooperative_groups;

// Problem constants
#define B_   8
#define KDIM 512
#define AA_  128
#define RTOT 32768          // 8*4096 encoder rows
#define BM   128            // rows per block
#define NBLK 256            // RTOT/BM — exactly 1 block/CU, co-resident

typedef __attribute__((ext_vector_type(8))) short short8;
typedef __attribute__((ext_vector_type(4))) float f32x4;

// ---- workspace layout (bytes) ----
#define WCT_OFF   0                         // ushort[256][512] = 262144
#define U_OFF     262144                    // float[128]
#define BIAS_OFF  262656                    // float[256]
#define NUM_OFF   263680                    // float[8*128]
#define S_OFF     267776                    // float[32768] raw scores

__device__ inline ushort f2bf(float f) {
    union { float f; unsigned u; } x; x.f = f;
    unsigned r = x.u + 0x7fffu + ((x.u >> 16) & 1u);  // RNE
    return (ushort)(r >> 16);
}

// ---------------- prep: WcT (transposed bf16 weights), bias, u = Pu@pv, zero num
__global__ void prep_kernel(const float* __restrict__ Wk, const float* __restrict__ bk,
                            const float* __restrict__ Wv, const float* __restrict__ bv,
                            const float* __restrict__ Pu, const float* __restrict__ pv,
                            ushort* __restrict__ wct, float* __restrict__ u,
                            float* __restrict__ bias, float* __restrict__ num) {
    int t = threadIdx.x;
    int base = blockIdx.x * 256 + t;
    for (int i = 0; i < 4; ++i) {
        int idx = base + i * 32768;
        int n = idx >> 9, k = idx & 511;
        float s = (n < 128) ? Wk[k * 128 + n] : Wv[k * 128 + (n - 128)];
        wct[idx] = f2bf(s);
    }
    if (blockIdx.x == 0) {
        if (t < 128) {
            float acc = 0.f;
            for (int c = 0; c < 128; ++c) acc += Pu[t * 128 + c] * pv[c];
            u[t] = acc;
        }
        bias[t] = (t < 128) ? bk[t] : bv[t - 128];
        for (int i = 0; i < 4; ++i) num[t + i * 256] = 0.f;
    }
}

// ======== mega kernel: gemm+score | softmax+wsum (v in regs) | bcast ========

#define LOAD_AB(AV, BV, K0)                                                     \
    do {                                                                        \
        _Pragma("unroll")                                                       \
        for (int i_ = 0; i_ < 2; ++i_) {                                        \
            int c_ = t + i_ * 512; int r_ = c_ >> 3, k8_ = (c_ & 7) * 8;        \
            const float4* sp_ = (const float4*)(enc + (size_t)(row0 + r_) * KDIM + (K0) + k8_); \
            AV[i_][0] = sp_[0]; AV[i_][1] = sp_[1];                             \
        }                                                                       \
        _Pragma("unroll")                                                       \
        for (int i_ = 0; i_ < 4; ++i_) {                                        \
            int c_ = t + i_ * 512; int n_ = c_ >> 3, k8_ = (c_ & 7) * 8;        \
            BV[i_] = *(const int4*)(wct + (size_t)n_ * KDIM + (K0) + k8_);      \
        }                                                                       \
    } while (0)

#define WRITE_AB(AV, BV)                                                        \
    do {                                                                        \
        _Pragma("unroll")                                                       \
        for (int i_ = 0; i_ < 2; ++i_) {                                        \
            int c_ = t + i_ * 512; int r_ = c_ >> 3, k8_ = (c_ & 7) * 8;        \
            int4 pk_;                                                           \
            pk_.x = (int)f2bf(AV[i_][0].x) | ((int)f2bf(AV[i_][0].y) << 16);    \
            pk_.y = (int)f2bf(AV[i_][0].z) | ((int)f2bf(AV[i_][0].w) << 16);    \
            pk_.z = (int)f2bf(AV[i_][1].x) | ((int)f2bf(AV[i_][1].y) << 16);    \
            pk_.w = (int)f2bf(AV[i_][1].z) | ((int)f2bf(AV[i_][1].w) << 16);    \
            *(int4*)&As[r_][k8_] = pk_;                                         \
        }                                                                       \
        _Pragma("unroll")                                                       \
        for (int i_ = 0; i_ < 4; ++i_) {                                        \
            int c_ = t + i_ * 512; int n_ = c_ >> 3, k8_ = (c_ & 7) * 8;        \
            *(int4*)&Bs[n_][k8_] = BV[i_];                                      \
        }                                                                       \
    } while (0)

#define COMPUTE_STEP()                                                          \
    do {                                                                        \
        _Pragma("unroll")                                                       \
        for (int kc_ = 0; kc_ < 2; ++kc_) {                                     \
            short8 afr_[4], bfr_[4];                                            \
            _Pragma("unroll")                                                   \
            for (int mt_ = 0; mt_ < 4; ++mt_)                                   \
                afr_[mt_] = *(const short8*)&As[wm * 64 + mt_ * 16 + m][kc_ * 32 + kb * 8]; \
            _Pragma("unroll")                                                   \
            for (int nt_ = 0; nt_ < 4; ++nt_)                                   \
                bfr_[nt_] = *(const short8*)&Bs[wn * 64 + nt_ * 16 + m][kc_ * 32 + kb * 8]; \
            _Pragma("unroll")                                                   \
            for (int mt_ = 0; mt_ < 4; ++mt_)                                   \
                _Pragma("unroll")                                               \
                for (int nt_ = 0; nt_ < 4; ++nt_)                               \
                    acc[mt_][nt_] = __builtin_amdgcn_mfma_f32_16x16x32_bf16(    \
                        afr_[mt_], bfr_[nt_], acc[mt_][nt_], 0, 0, 0);          \
        }                                                                       \
    } while (0)

__global__ __launch_bounds__(512, 2)
void mega_kernel(const float* __restrict__ enc, const ushort* __restrict__ wct,
                 const float* __restrict__ bias, const float* __restrict__ u,
                 float* __restrict__ sg, float* __restrict__ num,
                 float* __restrict__ out) {
    cg::grid_group grid = cg::this_grid();
    __shared__ ushort As[BM][72];       // 18432 B
    __shared__ ushort Bs[256][72];      // 36864 B
    __shared__ float sred[256];         //  1024 B
    __shared__ float wl[128];           //   512 B
    __shared__ float redA[9], redB[9];

    const int t = threadIdx.x;
    const int wv = t >> 6, l = t & 63;
    const int wm = wv >> 2, wn = wv & 3;      // wave grid 2(m) x 4(n)
    const int m = l & 15, kb = l >> 4;
    const int rg = kb;
    const int row0 = blockIdx.x * BM;
    const int b = row0 >> 12;                 // batch of this block's rows

    f32x4 acc[4][4] = {};

    // ---------- Phase 1: GEMM (pipelined: next-step loads fly across barriers)
    {
        float4 avA[2][2], avB[2][2];
        int4 bvA[4], bvB[4];
        LOAD_AB(avA, bvA, 0);
#pragma unroll
        for (int st = 0; st < 8; st += 2) {
            WRITE_AB(avA, bvA);
            if (st + 1 < 8) LOAD_AB(avB, bvB, (st + 1) * 64);
            __syncthreads();
            COMPUTE_STEP();
            __syncthreads();
            if (st + 1 < 8) {
                WRITE_AB(avB, bvB);
                if (st + 2 < 8) LOAD_AB(avA, bvA, (st + 2) * 64);
                __syncthreads();
                COMPUTE_STEP();
                __syncthreads();
            }
        }
    }

    // ---------- epilogue: scores (k-half) / relu-v kept in registers (v-half)
    if (wn < 2) {
#pragma unroll
        for (int mt = 0; mt < 4; ++mt) {
            float p[4] = {0.f, 0.f, 0.f, 0.f};
#pragma unroll
            for (int nt = 0; nt < 4; ++nt) {
                int col = wn * 64 + nt * 16 + m;          // 0..127
                float bsv = bias[col], uw = u[col];
#pragma unroll
                for (int j = 0; j < 4; ++j) {
                    float vv = acc[mt][nt][j] + bsv;
                    vv = vv > 0.f ? vv : 0.f;
                    p[j] += vv * uw;
                }
            }
#pragma unroll
            for (int j = 0; j < 4; ++j) {
                p[j] += __shfl_xor(p[j], 1);
                p[j] += __shfl_xor(p[j], 2);
                p[j] += __shfl_xor(p[j], 4);
                p[j] += __shfl_xor(p[j], 8);
            }
            if (m == 0) {
#pragma unroll
                for (int j = 0; j < 4; ++j)
                    sred[(wm * 64 + mt * 16 + rg * 4 + j) * 2 + wn] = p[j];
            }
        }
    } else {
#pragma unroll
        for (int mt = 0; mt < 4; ++mt)
#pragma unroll
            for (int nt = 0; nt < 4; ++nt) {
                int col = wn * 64 + nt * 16 + m;          // 128..255
                float bsv = bias[col];
#pragma unroll
                for (int j = 0; j < 4; ++j) {
                    float vv = acc[mt][nt][j] + bsv;
                    acc[mt][nt][j] = vv > 0.f ? vv : 0.f;
                }
            }
    }
    __syncthreads();
    if (t < 128) sg[row0 + t] = sred[t * 2] + sred[t * 2 + 1];

    grid.sync();

    // ---------- Phase 2: per-batch softmax stats (redundant per block) + wsum
    const float inv_s = 0.08838834764831843f;  // 1/sqrt(128)
    float vloc[8], mx = -1e30f;
#pragma unroll
    for (int it = 0; it < 8; ++it) {
        vloc[it] = sg[b * 4096 + it * 512 + t];
        mx = fmaxf(mx, vloc[it]);
    }
#pragma unroll
    for (int off = 1; off < 64; off <<= 1) mx = fmaxf(mx, __shfl_xor(mx, off));
    if (l == 0) redA[wv] = mx;
    __syncthreads();
    if (t == 0) {
        float x = redA[0];
        for (int i = 1; i < 8; ++i) x = fmaxf(x, redA[i]);
        redA[8] = x;
    }
    __syncthreads();
    float M = redA[8];
    float sm = 0.f;
#pragma unroll
    for (int it = 0; it < 8; ++it) sm += __expf((vloc[it] - M) * inv_s);
#pragma unroll
    for (int off = 1; off < 64; off <<= 1) sm += __shfl_xor(sm, off);
    if (l == 0) redB[wv] = sm;
    __syncthreads();
    if (t == 0) {
        float x = 0.f;
        for (int i = 0; i < 8; ++i) x += redB[i];
        redB[8] = 1.0f / x;
    }
    __syncthreads();
    float rS = redB[8];
    if (t < 128) wl[t] = __expf((sg[row0 + t] - M) * inv_s) * rS;
    __syncthreads();

    if (wn >= 2) {
#pragma unroll
        for (int nt = 0; nt < 4; ++nt) {
            float p = 0.f;
#pragma unroll
            for (int mt = 0; mt < 4; ++mt)
#pragma unroll
                for (int j = 0; j < 4; ++j)
                    p += wl[wm * 64 + mt * 16 + rg * 4 + j] * acc[mt][nt][j];
            p += __shfl_xor(p, 16);
            p += __shfl_xor(p, 32);
            if (l < 16) sred[wm * 128 + (wn - 2) * 64 + nt * 16 + m] = p;
        }
    }
    __syncthreads();
    if (t < 128) atomicAdd(&num[b * 128 + t], sred[t] + sred[128 + t]);

    grid.sync();

    // ---------- Phase 3: broadcast out[b,i,:] = num[b,:]
    {
        const float4* n4 = (const float4*)num;
        float4* o4 = (float4*)out;
        float4 nv = n4[b * 32 + (t & 31)];
        size_t base = (size_t)blockIdx.x * 4096;
#pragma unroll
        for (int it = 0; it < 8; ++it)
            o4[base + it * 512 + t] = nv;
    }
}

extern "C" void kernel_launch(void* const* d_in, const int* in_sizes, int n_in,
                              void* d_out, int out_size, void* d_ws, size_t ws_size,
                              hipStream_t stream) {
    const float* enc = (const float*)d_in[0];
    // d_in[1]=decoder, d_in[2]=Wq, d_in[3]=bq, d_in[8]=Pw: provably unused
    // (softmax is shift-invariant in q_term, which is constant per decoder row)
    const float* Wk = (const float*)d_in[4];
    const float* bk = (const float*)d_in[5];
    const float* Wv = (const float*)d_in[6];
    const float* bv = (const float*)d_in[7];
    const float* Pu = (const float*)d_in[9];
    const float* pv = (const float*)d_in[10];

    char* ws = (char*)d_ws;
    ushort* wct  = (ushort*)(ws + WCT_OFF);
    float*  u    = (float*)(ws + U_OFF);
    float*  bias = (float*)(ws + BIAS_OFF);
    float*  num  = (float*)(ws + NUM_OFF);
    float*  sg   = (float*)(ws + S_OFF);
    float*  out  = (float*)d_out;

    prep_kernel<<<128, 256, 0, stream>>>(Wk, bk, Wv, bv, Pu, pv, wct, u, bias, num);

    void* args[7] = {(void*)&enc, (void*)&wct, (void*)&bias, (void*)&u,
                     (void*)&sg, (void*)&num, (void*)&out};
    hipLaunchCooperativeKernel((void*)mega_kernel, dim3(NBLK), dim3(512),
                               args, 0, stream);
}

// Round 7
// 214.306 us; speedup vs baseline: 1.2278x; 1.2278x over previous
//
#include <hip/hip_runtime.h>
#include <hip/hip_bf16.h>

// Problem constants
#define B_   8
#define KDIM 512
#define AA_  128
#define RTOT 32768          // 8*4096 encoder rows
#define NDIM 256            // k(128) | v(128) fused output cols

typedef __attribute__((ext_vector_type(8))) short short8;
typedef __attribute__((ext_vector_type(4))) float f32x4;

// ---- workspace layout (bytes) ----
#define WCT_OFF   0                         // ushort[256][512] = 262144
#define U_OFF     262144                    // float[128]
#define BIAS_OFF  262656                    // float[256]
#define PARTS_OFF 263680                    // float[64][128] = 32768
#define S_OFF     296448                    // float[32768] = 131072 (raw scores)
#define VB_OFF    427520                    // ushort[32768*128] = 8388608 (v, bf16)

__device__ inline ushort f2bf(float f) {
    union { float f; unsigned u; } x; x.f = f;
    unsigned r = x.u + 0x7fffu + ((x.u >> 16) & 1u);  // RNE
    return (ushort)(r >> 16);
}
__device__ inline float bf2f(ushort s) {
    union { unsigned u; float f; } x; x.u = ((unsigned)s) << 16;
    return x.f;
}

// ---------------- prep: WcT (transposed bf16 weights), bias, u = Pu@pv
__global__ void prep_kernel(const float* __restrict__ Wk, const float* __restrict__ bk,
                            const float* __restrict__ Wv, const float* __restrict__ bv,
                            const float* __restrict__ Pu, const float* __restrict__ pv,
                            ushort* __restrict__ wct, float* __restrict__ u,
                            float* __restrict__ bias) {
    int t = threadIdx.x;
    int base = blockIdx.x * 256 + t;
    for (int i = 0; i < 4; ++i) {
        int idx = base + i * 32768;
        int n = idx >> 9, k = idx & 511;
        float s = (n < 128) ? Wk[k * 128 + n] : Wv[k * 128 + (n - 128)];
        wct[idx] = f2bf(s);
    }
    if (blockIdx.x == 0) {
        if (t < 128) {
            float acc = 0.f;
            for (int c = 0; c < 128; ++c) acc += Pu[t * 128 + c] * pv[c];
            u[t] = acc;
        }
        bias[t] = (t < 128) ? bk[t] : bv[t - 128];
    }
}

// ---------------- fused GEMM (software-pipelined register prefetch):
//   kv[r][0:256] = relu(enc[r,:] @ [Wk|Wv] + [bk|bv])
//   s[r] = kv[r][0:128] . u ;  vbuf[r][0:128] = bf16(kv[r][128:256])
__global__ __launch_bounds__(512, 4)
void gemm_fused(const float* __restrict__ enc, const ushort* __restrict__ wct,
                const float* __restrict__ bias, const float* __restrict__ u,
                ushort* __restrict__ vbuf, float* __restrict__ sout) {
    __shared__ ushort As[64][72];       //  9216 B
    __shared__ ushort Bs[256][72];      // 36864 B
    __shared__ float s_red[64][2];      //   512 B
    const int t = threadIdx.x;
    const int wv = t >> 6, l = t & 63;
    const int wm = wv >> 2, wn = wv & 3;     // wave grid 2(m) x 4(n)
    const int m = l & 15, kb = l >> 4;
    const int row0 = blockIdx.x * 64;

    // staging assignments (fixed per thread)
    const int ar = t >> 3, ak8 = (t & 7) * 8;            // A: row, k-offset
    const float* aptr = enc + (size_t)(row0 + ar) * KDIM + ak8;

    f32x4 acc[2][4] = {};
    float4 a0, a1;
    int4 bp[4];

    // prologue: loads for k0 = 0
    a0 = *(const float4*)aptr;
    a1 = *(const float4*)(aptr + 4);
#pragma unroll
    for (int i = 0; i < 4; ++i) {
        int c = t + i * 512, n = c >> 3, k8 = (c & 7) * 8;
        bp[i] = *(const int4*)(wct + (size_t)n * KDIM + k8);
    }

    for (int st = 0; st < 8; ++st) {
        // write staged registers to LDS
        {
            int4 pk;
            pk.x = (int)f2bf(a0.x) | ((int)f2bf(a0.y) << 16);
            pk.y = (int)f2bf(a0.z) | ((int)f2bf(a0.w) << 16);
            pk.z = (int)f2bf(a1.x) | ((int)f2bf(a1.y) << 16);
            pk.w = (int)f2bf(a1.z) | ((int)f2bf(a1.w) << 16);
            *(int4*)&As[ar][ak8] = pk;
#pragma unroll
            for (int i = 0; i < 4; ++i) {
                int c = t + i * 512, n = c >> 3, k8 = (c & 7) * 8;
                *(int4*)&Bs[n][k8] = bp[i];
            }
        }
        __syncthreads();
        // issue NEXT step's loads now — they fly across the MFMA block
        if (st < 7) {
            const float* ap = aptr + (st + 1) * 64;
            a0 = *(const float4*)ap;
            a1 = *(const float4*)(ap + 4);
#pragma unroll
            for (int i = 0; i < 4; ++i) {
                int c = t + i * 512, n = c >> 3, k8 = (c & 7) * 8;
                bp[i] = *(const int4*)(wct + (size_t)n * KDIM + (st + 1) * 64 + k8);
            }
        }
        // compute on current LDS tile
#pragma unroll
        for (int kc = 0; kc < 2; ++kc) {
            short8 afr[2], bfr[4];
#pragma unroll
            for (int mt = 0; mt < 2; ++mt)
                afr[mt] = *(const short8*)&As[wm * 32 + mt * 16 + m][kc * 32 + kb * 8];
#pragma unroll
            for (int nt = 0; nt < 4; ++nt)
                bfr[nt] = *(const short8*)&Bs[wn * 64 + nt * 16 + m][kc * 32 + kb * 8];
#pragma unroll
            for (int mt = 0; mt < 2; ++mt)
#pragma unroll
                for (int nt = 0; nt < 4; ++nt)
                    acc[mt][nt] = __builtin_amdgcn_mfma_f32_16x16x32_bf16(
                        afr[mt], bfr[nt], acc[mt][nt], 0, 0, 0);
        }
        __syncthreads();
    }

    // ---- epilogue ----
    const int rg = kb;
    if (wn < 2) {
        // k half: per-row dot with u
#pragma unroll
        for (int mt = 0; mt < 2; ++mt) {
            float p[4] = {0.f, 0.f, 0.f, 0.f};
#pragma unroll
            for (int nt = 0; nt < 4; ++nt) {
                int col = wn * 64 + nt * 16 + m;        // 0..127
                float bsv = bias[col], uw = u[col];
#pragma unroll
                for (int j = 0; j < 4; ++j) {
                    float vvv = acc[mt][nt][j] + bsv;
                    vvv = vvv > 0.f ? vvv : 0.f;
                    p[j] += vvv * uw;
                }
            }
#pragma unroll
            for (int j = 0; j < 4; ++j) {
                p[j] += __shfl_xor(p[j], 1);
                p[j] += __shfl_xor(p[j], 2);
                p[j] += __shfl_xor(p[j], 4);
                p[j] += __shfl_xor(p[j], 8);
            }
            if (m == 0) {
#pragma unroll
                for (int j = 0; j < 4; ++j)
                    s_red[wm * 32 + mt * 16 + rg * 4 + j][wn] = p[j];
            }
        }
    } else {
        // v half: bias + relu -> bf16 store
#pragma unroll
        for (int mt = 0; mt < 2; ++mt) {
#pragma unroll
            for (int nt = 0; nt < 4; ++nt) {
                int col = wn * 64 + nt * 16 + m;        // 128..255
                float bsv = bias[col];
#pragma unroll
                for (int j = 0; j < 4; ++j) {
                    int rowl = wm * 32 + mt * 16 + rg * 4 + j;
                    float vvv = acc[mt][nt][j] + bsv;
                    vvv = vvv > 0.f ? vvv : 0.f;
                    vbuf[(size_t)(row0 + rowl) * AA_ + (col - 128)] = f2bf(vvv);
                }
            }
        }
    }
    __syncthreads();
    if (t < 64) sout[row0 + t] = s_red[t][0] + s_red[t][1];
}

// ---------------- wsum (softmax fused): block = (b,ch); parts[blk][d] =
//   sum_{j in chunk} softmax_j(s) * v[j,d]
__global__ __launch_bounds__(256)
void wsum_kernel(const ushort* __restrict__ vbuf, const float* __restrict__ sg,
                 float* __restrict__ parts) {
    __shared__ float redM[5], redS[5];
    __shared__ float pw[4][128];
    const int blk = blockIdx.x;                 // 0..63
    const int b = blk >> 3, ch = blk & 7;
    const int t = threadIdx.x, wv = t >> 6, l = t & 63;
    const float inv_s = 0.08838834764831843f;   // 1/sqrt(128)

    // softmax stats over batch b (redundant per chunk-block; 16 KB from L2)
    float vl[16], mx = -1e30f;
#pragma unroll
    for (int i = 0; i < 16; ++i) {
        vl[i] = sg[b * 4096 + i * 256 + t];
        mx = fmaxf(mx, vl[i]);
    }
#pragma unroll
    for (int off = 1; off < 64; off <<= 1) mx = fmaxf(mx, __shfl_xor(mx, off));
    if (l == 0) redM[wv] = mx;
    __syncthreads();
    if (t == 0) redM[4] = fmaxf(fmaxf(redM[0], redM[1]), fmaxf(redM[2], redM[3]));
    __syncthreads();
    const float M = redM[4];
    float sm = 0.f;
#pragma unroll
    for (int i = 0; i < 16; ++i) sm += __expf((vl[i] - M) * inv_s);
#pragma unroll
    for (int off = 1; off < 64; off <<= 1) sm += __shfl_xor(sm, off);
    if (l == 0) redS[wv] = sm;
    __syncthreads();
    if (t == 0) redS[4] = 1.0f / (redS[0] + redS[1] + redS[2] + redS[3]);
    __syncthreads();
    const float rS = redS[4];

    // weighted sum over this chunk's 512 rows
    const int rg = l >> 4, d8 = (l & 15) * 8;
    const int rbase = b * 4096 + ch * 512;
    float acc[8] = {};
    for (int it = 0; it < 32; ++it) {
        int r = rbase + it * 16 + wv * 4 + rg;
        float wj = __expf((sg[r] - M) * inv_s) * rS;
        short8 vvv = *(const short8*)(vbuf + (size_t)r * AA_ + d8);
#pragma unroll
        for (int j = 0; j < 8; ++j)
            acc[j] += wj * bf2f((ushort)vvv[j]);
    }
#pragma unroll
    for (int j = 0; j < 8; ++j) {
        acc[j] += __shfl_xor(acc[j], 16);
        acc[j] += __shfl_xor(acc[j], 32);
    }
    if (l < 16) {
#pragma unroll
        for (int j = 0; j < 8; ++j) pw[wv][d8 + j] = acc[j];
    }
    __syncthreads();
    if (t < 128) parts[blk * 128 + t] = pw[0][t] + pw[1][t] + pw[2][t] + pw[3][t];
}

// ---------------- broadcast: out[b,i,:] = sum_ch parts[b*8+ch][:]
__global__ __launch_bounds__(256)
void bcast_kernel(const float* __restrict__ parts, float4* __restrict__ out) {
    __shared__ float4 nv[32];
    const int t = threadIdx.x;
    const int c = blockIdx.x * 256 + t;
    const int b = (blockIdx.x * 1024) >> 19;     // batch constant per block
    if (t < 32) {
        const float4* p4 = (const float4*)parts;
        float4 s = {0.f, 0.f, 0.f, 0.f};
#pragma unroll
        for (int ch = 0; ch < 8; ++ch) {
            float4 q = p4[(b * 8 + ch) * 32 + t];
            s.x += q.x; s.y += q.y; s.z += q.z; s.w += q.w;
        }
        nv[t] = s;
    }
    __syncthreads();
    out[c] = nv[t & 31];
}

extern "C" void kernel_launch(void* const* d_in, const int* in_sizes, int n_in,
                              void* d_out, int out_size, void* d_ws, size_t ws_size,
                              hipStream_t stream) {
    const float* enc = (const float*)d_in[0];
    // d_in[1]=decoder, d_in[2]=Wq, d_in[3]=bq, d_in[8]=Pw: provably unused
    // (softmax is shift-invariant in q_term, which is constant per decoder row)
    const float* Wk = (const float*)d_in[4];
    const float* bk = (const float*)d_in[5];
    const float* Wv = (const float*)d_in[6];
    const float* bv = (const float*)d_in[7];
    const float* Pu = (const float*)d_in[9];
    const float* pv = (const float*)d_in[10];

    char* ws = (char*)d_ws;
    ushort* wct   = (ushort*)(ws + WCT_OFF);
    float*  u     = (float*)(ws + U_OFF);
    float*  bias  = (float*)(ws + BIAS_OFF);
    float*  parts = (float*)(ws + PARTS_OFF);
    float*  sg    = (float*)(ws + S_OFF);
    ushort* vbuf  = (ushort*)(ws + VB_OFF);

    prep_kernel<<<128, 256, 0, stream>>>(Wk, bk, Wv, bv, Pu, pv, wct, u, bias);
    gemm_fused<<<RTOT / 64, 512, 0, stream>>>(enc, wct, bias, u, vbuf, sg);
    wsum_kernel<<<64, 256, 0, stream>>>(vbuf, sg, parts);
    bcast_kernel<<<4096, 256, 0, stream>>>(parts, (float4*)d_out);
}

// Round 8
// 181.393 us; speedup vs baseline: 1.4506x; 1.1814x over previous
//
#include <hip/hip_runtime.h>
#include <hip/hip_bf16.h>

// Problem constants
#define B_   8
#define KDIM 512
#define AA_  128
#define RTOT 32768          // 8*4096 encoder rows
#define BM   32             // rows per block
#define NGRID (RTOT/BM)     // 1024 blocks -> 4 blocks/CU

typedef __attribute__((ext_vector_type(8))) short short8;
typedef __attribute__((ext_vector_type(4))) float f32x4;

// ---- workspace layout (bytes) ----
#define WCT_OFF   0                         // ushort[256][512] = 262144
#define U_OFF     262144                    // float[128]
#define BIAS_OFF  262656                    // float[256]
#define PARTS_OFF 263680                    // float[64][128] = 32768
#define S_OFF     296448                    // float[32768] = 131072 (raw scores)
#define VB_OFF    427520                    // ushort[32768*128] = 8388608 (v, bf16)

__device__ inline ushort f2bf(float f) {
    union { float f; unsigned u; } x; x.f = f;
    unsigned r = x.u + 0x7fffu + ((x.u >> 16) & 1u);  // RNE
    return (ushort)(r >> 16);
}
__device__ inline float bf2f(ushort s) {
    union { unsigned u; float f; } x; x.u = ((unsigned)s) << 16;
    return x.f;
}

// async global->LDS, 16 B per lane (wave writes 1 KB linear at base+lane*16)
__device__ __forceinline__ void glds16(const void* g, void* l) {
    __builtin_amdgcn_global_load_lds(
        (const __attribute__((address_space(1))) void*)g,
        (__attribute__((address_space(3))) void*)l, 16, 0, 0);
}

// ---------------- prep: WcT (transposed bf16 weights), bias, u = Pu@pv
__global__ void prep_kernel(const float* __restrict__ Wk, const float* __restrict__ bk,
                            const float* __restrict__ Wv, const float* __restrict__ bv,
                            const float* __restrict__ Pu, const float* __restrict__ pv,
                            ushort* __restrict__ wct, float* __restrict__ u,
                            float* __restrict__ bias) {
    int t = threadIdx.x;
    int base = blockIdx.x * 256 + t;
    for (int i = 0; i < 4; ++i) {
        int idx = base + i * 32768;
        int n = idx >> 9, k = idx & 511;
        float s = (n < 128) ? Wk[k * 128 + n] : Wv[k * 128 + (n - 128)];
        wct[idx] = f2bf(s);
    }
    if (blockIdx.x == 0) {
        if (t < 128) {
            float acc = 0.f;
            for (int c = 0; c < 128; ++c) acc += Pu[t * 128 + c] * pv[c];
            u[t] = acc;
        }
        bias[t] = (t < 128) ? bk[t] : bv[t - 128];
    }
}

// ---------------- fused GEMM:
//   kv[r][0:256] = relu(enc[r,:] @ [Wk|Wv] + [bk|bv])
//   s[r] = kv[r][0:128] . u ;  vbuf[r][0:128] = bf16(kv[r][128:256])
// B staged via global_load_lds (linear LDS), A via register convert w/ prefetch.
__global__ __launch_bounds__(256, 4)
void gemm_fused(const float* __restrict__ enc, const ushort* __restrict__ wct,
                const float* __restrict__ bias, const float* __restrict__ u,
                ushort* __restrict__ vbuf, float* __restrict__ sout) {
    __shared__ ushort As[BM][72];       //  4608 B (padded: reg ds_write, no DMA)
    __shared__ ushort Bs[256][64];      // 32768 B (LINEAR: global_load_lds dest)
    __shared__ float s_red[BM][2];      //   256 B
    const int t = threadIdx.x;
    const int wv = t >> 6, l = t & 63;
    const int m = l & 15, kb = l >> 4;
    const int rg = kb;
    const int row0 = blockIdx.x * BM;

    // A staging assignment: thread t owns row t>>3, 8-elem chunk (t&7)*8
    const int ar = t >> 3, ak8 = (t & 7) * 8;
    const float* aptr = enc + (size_t)(row0 + ar) * KDIM + ak8;

    // B staging assignment: per K-step, wave wv DMAs chunks c = wv*8+i (1 KB each)
    const int brow = (l >> 3);          // + c*8
    const int bcolB = (l & 7) << 4;     // byte offset within 128 B row

    f32x4 acc[2][4] = {};
    float4 a0, a1;

    // prologue: A loads for step 0
    a0 = *(const float4*)aptr;
    a1 = *(const float4*)(aptr + 4);

    for (int st = 0; st < 8; ++st) {
        // issue B DMA first (8 x 1KB per wave), then A convert+ds_write overlaps
        {
            const char* gbase = (const char*)wct + (size_t)st * 128 + bcolB;
#pragma unroll
            for (int i = 0; i < 8; ++i) {
                int c = (wv << 3) | i;
                int row = (c << 3) + brow;
                glds16(gbase + (size_t)row * 1024,
                       (char*)Bs + c * 1024 + l * 16);
            }
            int4 pk;
            pk.x = (int)f2bf(a0.x) | ((int)f2bf(a0.y) << 16);
            pk.y = (int)f2bf(a0.z) | ((int)f2bf(a0.w) << 16);
            pk.z = (int)f2bf(a1.x) | ((int)f2bf(a1.y) << 16);
            pk.w = (int)f2bf(a1.z) | ((int)f2bf(a1.w) << 16);
            *(int4*)&As[ar][ak8] = pk;
        }
        __syncthreads();
        // prefetch next step's A while MFMA runs
        if (st < 7) {
            const float* ap = aptr + (st + 1) * 64;
            a0 = *(const float4*)ap;
            a1 = *(const float4*)(ap + 4);
        }
#pragma unroll
        for (int kc = 0; kc < 2; ++kc) {
            short8 afr[2], bfr[4];
#pragma unroll
            for (int mt = 0; mt < 2; ++mt)
                afr[mt] = *(const short8*)&As[mt * 16 + m][kc * 32 + kb * 8];
#pragma unroll
            for (int nt = 0; nt < 4; ++nt)
                bfr[nt] = *(const short8*)&Bs[wv * 64 + nt * 16 + m][kc * 32 + kb * 8];
#pragma unroll
            for (int mt = 0; mt < 2; ++mt)
#pragma unroll
                for (int nt = 0; nt < 4; ++nt)
                    acc[mt][nt] = __builtin_amdgcn_mfma_f32_16x16x32_bf16(
                        afr[mt], bfr[nt], acc[mt][nt], 0, 0, 0);
        }
        __syncthreads();
    }

    // ---- epilogue: wave's cols = wv*64 + nt*16 + m ----
    if (wv < 2) {
        // k half (cols 0..127): per-row dot with u
#pragma unroll
        for (int mt = 0; mt < 2; ++mt) {
            float p[4] = {0.f, 0.f, 0.f, 0.f};
#pragma unroll
            for (int nt = 0; nt < 4; ++nt) {
                int col = wv * 64 + nt * 16 + m;
                float bsv = bias[col], uw = u[col];
#pragma unroll
                for (int j = 0; j < 4; ++j) {
                    float vvv = acc[mt][nt][j] + bsv;
                    vvv = vvv > 0.f ? vvv : 0.f;
                    p[j] += vvv * uw;
                }
            }
#pragma unroll
            for (int j = 0; j < 4; ++j) {
                p[j] += __shfl_xor(p[j], 1);
                p[j] += __shfl_xor(p[j], 2);
                p[j] += __shfl_xor(p[j], 4);
                p[j] += __shfl_xor(p[j], 8);
            }
            if (m == 0) {
#pragma unroll
                for (int j = 0; j < 4; ++j)
                    s_red[mt * 16 + rg * 4 + j][wv] = p[j];
            }
        }
    } else {
        // v half (cols 128..255): bias + relu -> bf16 store
#pragma unroll
        for (int mt = 0; mt < 2; ++mt) {
#pragma unroll
            for (int nt = 0; nt < 4; ++nt) {
                int col = wv * 64 + nt * 16 + m;      // 128..255
                float bsv = bias[col];
#pragma unroll
                for (int j = 0; j < 4; ++j) {
                    int rowl = mt * 16 + rg * 4 + j;
                    float vvv = acc[mt][nt][j] + bsv;
                    vvv = vvv > 0.f ? vvv : 0.f;
                    vbuf[(size_t)(row0 + rowl) * AA_ + (col - 128)] = f2bf(vvv);
                }
            }
        }
    }
    __syncthreads();
    if (t < BM) sout[row0 + t] = s_red[t][0] + s_red[t][1];
}

// ---------------- wsum (softmax fused): block = (b,ch); parts[blk][d] =
//   sum_{j in chunk} softmax_j(s) * v[j,d]
__global__ __launch_bounds__(256)
void wsum_kernel(const ushort* __restrict__ vbuf, const float* __restrict__ sg,
                 float* __restrict__ parts) {
    __shared__ float redM[5], redS[5];
    __shared__ float pw[4][128];
    const int blk = blockIdx.x;                 // 0..63
    const int b = blk >> 3, ch = blk & 7;
    const int t = threadIdx.x, wv = t >> 6, l = t & 63;
    const float inv_s = 0.08838834764831843f;   // 1/sqrt(128)

    // softmax stats over batch b (redundant per chunk-block; 16 KB from L2)
    float vl[16], mx = -1e30f;
#pragma unroll
    for (int i = 0; i < 16; ++i) {
        vl[i] = sg[b * 4096 + i * 256 + t];
        mx = fmaxf(mx, vl[i]);
    }
#pragma unroll
    for (int off = 1; off < 64; off <<= 1) mx = fmaxf(mx, __shfl_xor(mx, off));
    if (l == 0) redM[wv] = mx;
    __syncthreads();
    if (t == 0) redM[4] = fmaxf(fmaxf(redM[0], redM[1]), fmaxf(redM[2], redM[3]));
    __syncthreads();
    const float M = redM[4];
    float sm = 0.f;
#pragma unroll
    for (int i = 0; i < 16; ++i) sm += __expf((vl[i] - M) * inv_s);
#pragma unroll
    for (int off = 1; off < 64; off <<= 1) sm += __shfl_xor(sm, off);
    if (l == 0) redS[wv] = sm;
    __syncthreads();
    if (t == 0) redS[4] = 1.0f / (redS[0] + redS[1] + redS[2] + redS[3]);
    __syncthreads();
    const float rS = redS[4];

    // weighted sum over this chunk's 512 rows
    const int rg = l >> 4, d8 = (l & 15) * 8;
    const int rbase = b * 4096 + ch * 512;
    float acc[8] = {};
    for (int it = 0; it < 32; ++it) {
        int r = rbase + it * 16 + wv * 4 + rg;
        float wj = __expf((sg[r] - M) * inv_s) * rS;
        short8 vvv = *(const short8*)(vbuf + (size_t)r * AA_ + d8);
#pragma unroll
        for (int j = 0; j < 8; ++j)
            acc[j] += wj * bf2f((ushort)vvv[j]);
    }
#pragma unroll
    for (int j = 0; j < 8; ++j) {
        acc[j] += __shfl_xor(acc[j], 16);
        acc[j] += __shfl_xor(acc[j], 32);
    }
    if (l < 16) {
#pragma unroll
        for (int j = 0; j < 8; ++j) pw[wv][d8 + j] = acc[j];
    }
    __syncthreads();
    if (t < 128) parts[blk * 128 + t] = pw[0][t] + pw[1][t] + pw[2][t] + pw[3][t];
}

// ---------------- broadcast: out[b,i,:] = sum_ch parts[b*8+ch][:]
__global__ __launch_bounds__(256)
void bcast_kernel(const float* __restrict__ parts, float4* __restrict__ out) {
    __shared__ float4 nv[32];
    const int t = threadIdx.x;
    const int c = blockIdx.x * 256 + t;
    const int b = (blockIdx.x * 1024) >> 19;     // batch constant per block
    if (t < 32) {
        const float4* p4 = (const float4*)parts;
        float4 s = {0.f, 0.f, 0.f, 0.f};
#pragma unroll
        for (int ch = 0; ch < 8; ++ch) {
            float4 q = p4[(b * 8 + ch) * 32 + t];
            s.x += q.x; s.y += q.y; s.z += q.z; s.w += q.w;
        }
        nv[t] = s;
    }
    __syncthreads();
    out[c] = nv[t & 31];
}

extern "C" void kernel_launch(void* const* d_in, const int* in_sizes, int n_in,
                              void* d_out, int out_size, void* d_ws, size_t ws_size,
                              hipStream_t stream) {
    const float* enc = (const float*)d_in[0];
    // d_in[1]=decoder, d_in[2]=Wq, d_in[3]=bq, d_in[8]=Pw: provably unused
    // (softmax is shift-invariant in q_term, which is constant per decoder row)
    const float* Wk = (const float*)d_in[4];
    const float* bk = (const float*)d_in[5];
    const float* Wv = (const float*)d_in[6];
    const float* bv = (const float*)d_in[7];
    const float* Pu = (const float*)d_in[9];
    const float* pv = (const float*)d_in[10];

    char* ws = (char*)d_ws;
    ushort* wct   = (ushort*)(ws + WCT_OFF);
    float*  u     = (float*)(ws + U_OFF);
    float*  bias  = (float*)(ws + BIAS_OFF);
    float*  parts = (float*)(ws + PARTS_OFF);
    float*  sg    = (float*)(ws + S_OFF);
    ushort* vbuf  = (ushort*)(ws + VB_OFF);

    prep_kernel<<<128, 256, 0, stream>>>(Wk, bk, Wv, bv, Pu, pv, wct, u, bias);
    gemm_fused<<<NGRID, 256, 0, stream>>>(enc, wct, bias, u, vbuf, sg);
    wsum_kernel<<<64, 256, 0, stream>>>(vbuf, sg, parts);
    bcast_kernel<<<4096, 256, 0, stream>>>(parts, (float4*)d_out);
}

// Round 10
// 177.271 us; speedup vs baseline: 1.4843x; 1.0233x over previous
//
#include <hip/hip_runtime.h>
#include <hip/hip_bf16.h>

// Problem constants
#define B_   8
#define KDIM 512
#define AA_  128
#define RTOT 32768          // 8*4096 encoder rows
#define BM   64             // rows per block
#define NGRID (RTOT/BM)     // 512 blocks -> exactly 2 blocks/CU

typedef __attribute__((ext_vector_type(8))) short short8;
typedef __attribute__((ext_vector_type(4))) float f32x4;

// ---- workspace layout (bytes) ----
#define WCT_OFF   0                         // ushort[256][512] = 262144 (SWIZZLED)
#define U_OFF     262144                    // float[128]
#define BIAS_OFF  262656                    // float[256]
#define PARTS_OFF 263680                    // float[256][128] = 131072
#define S_OFF     394752                    // float[32768] = 131072 (raw scores)
#define VB_OFF    525824                    // ushort[32768*128] = 8388608 (v, bf16)

__device__ inline ushort f2bf(float f) {
    union { float f; unsigned u; } x; x.f = f;
    unsigned r = x.u + 0x7fffu + ((x.u >> 16) & 1u);  // RNE
    return (ushort)(r >> 16);
}
__device__ inline float bf2f(ushort s) {
    union { unsigned u; float f; } x; x.u = ((unsigned)s) << 16;
    return x.f;
}

// async global->LDS, 16 B per lane (wave writes 1 KB linear at base+lane*16)
__device__ __forceinline__ void glds16(const void* g, void* l) {
    __builtin_amdgcn_global_load_lds(
        (const __attribute__((address_space(1))) void*)g,
        (__attribute__((address_space(3))) void*)l, 16, 0, 0);
}

// ---------------- prep: swizzled WcT (bf16), bias, u = Pu@pv
// wct[n][dst_k]: 16B-slot s within each 64-k step holds source chunk j = s^(n&7)
// so the linear global_load_lds lands a bank-conflict-free layout in LDS.
__global__ void prep_kernel(const float* __restrict__ Wk, const float* __restrict__ bk,
                            const float* __restrict__ Wv, const float* __restrict__ bv,
                            const float* __restrict__ Pu, const float* __restrict__ pv,
                            ushort* __restrict__ wct, float* __restrict__ u,
                            float* __restrict__ bias) {
    int t = threadIdx.x;
    int base = blockIdx.x * 256 + t;
    for (int i = 0; i < 4; ++i) {
        int idx = base + i * 32768;
        int n = idx >> 9, kdst = idx & 511;
        int st = kdst >> 6, s = (kdst >> 3) & 7, e = kdst & 7;
        int j = s ^ (n & 7);
        int ksrc = st * 64 + j * 8 + e;
        float v = (n < 128) ? Wk[ksrc * 128 + n] : Wv[ksrc * 128 + (n - 128)];
        wct[idx] = f2bf(v);
    }
    if (blockIdx.x == 0) {
        if (t < 128) {
            float acc = 0.f;
            for (int c = 0; c < 128; ++c) acc += Pu[t * 128 + c] * pv[c];
            u[t] = acc;
        }
        bias[t] = (t < 128) ? bk[t] : bv[t - 128];
    }
}

// ---------------- fused GEMM, counted-vmcnt double-buffered pipeline:
//   kv[r][0:256] = relu(enc[r,:] @ [Wk|Wv] + [bk|bv])
//   s[r] = kv[r][0:128] . u ;  vbuf[r][0:128] = bf16(kv[r][128:256])
__global__ __launch_bounds__(256, 2)
void gemm_fused(const float* __restrict__ enc, const ushort* __restrict__ wct,
                const float* __restrict__ bias, const float* __restrict__ u,
                ushort* __restrict__ vbuf, float* __restrict__ sout) {
    __shared__ ushort Bs[2][256 * 64];  // 65536 B, LINEAR dest for DMA (swizzled content)
    __shared__ ushort As[BM][72];       //  9216 B (144B stride: 2-way read conflicts = free)
    __shared__ float s_red[BM][2];      //   512 B
    const int t = threadIdx.x;
    const int wv = t >> 6, l = t & 63;
    const int m = l & 15, kb = l >> 4;
    const int row0 = blockIdx.x * BM;

    // A staging: thread t owns rows t>>3 and (t>>3)+32, 8-elem chunk (t&7)*8
    const int ar0 = t >> 3, ak8 = (t & 7) * 8;
    const float* ap0 = enc + (size_t)(row0 + ar0) * KDIM + ak8;
    const float* ap1 = ap0 + (size_t)32 * KDIM;

    // B DMA: wave wv stages chunks c=wv*8+i (1 KB each); lane l: row c*8+(l>>3),
    // 16B slot l&7 (source pre-swizzled, LDS stays linear)
    const char* wct_c = (const char*)wct;

    f32x4 acc[4][4] = {};
    float4 a0, a1, a2, a3;

    // prologue: A loads for step 0, then B DMA for step 0 (order matters for vmcnt)
    a0 = *(const float4*)ap0; a1 = *(const float4*)(ap0 + 4);
    a2 = *(const float4*)ap1; a3 = *(const float4*)(ap1 + 4);
#pragma unroll
    for (int i = 0; i < 8; ++i) {
        int c = (wv << 3) | i;
        int row = (c << 3) + (l >> 3);
        glds16(wct_c + (size_t)row * 1024 + ((l & 7) << 4),
               (char*)&Bs[0][0] + c * 1024 + l * 16);
    }

#pragma unroll
    for (int st = 0; st < 8; ++st) {
        const int bufc = st & 1;
        // pack current A regs -> LDS (compiler inserts vmcnt for a-regs, leaves DMAs)
        {
            int4 pk;
            pk.x = (int)f2bf(a0.x) | ((int)f2bf(a0.y) << 16);
            pk.y = (int)f2bf(a0.z) | ((int)f2bf(a0.w) << 16);
            pk.z = (int)f2bf(a1.x) | ((int)f2bf(a1.y) << 16);
            pk.w = (int)f2bf(a1.z) | ((int)f2bf(a1.w) << 16);
            *(int4*)&As[ar0][ak8] = pk;
            pk.x = (int)f2bf(a2.x) | ((int)f2bf(a2.y) << 16);
            pk.y = (int)f2bf(a2.z) | ((int)f2bf(a2.w) << 16);
            pk.z = (int)f2bf(a3.x) | ((int)f2bf(a3.y) << 16);
            pk.w = (int)f2bf(a3.z) | ((int)f2bf(a3.w) << 16);
            *(int4*)&As[ar0 + 32][ak8] = pk;
        }
        if (st < 7) {
            // prefetch A for st+1 (issued BEFORE next B DMA: vmcnt ordering)
            const float* p0 = ap0 + (st + 1) * 64;
            const float* p1 = ap1 + (st + 1) * 64;
            a0 = *(const float4*)p0; a1 = *(const float4*)(p0 + 4);
            a2 = *(const float4*)p1; a3 = *(const float4*)(p1 + 4);
            // B DMA for st+1 into the other buffer — stays in flight across MFMA
            const char* gb = wct_c + (size_t)(st + 1) * 128;
#pragma unroll
            for (int i = 0; i < 8; ++i) {
                int c = (wv << 3) | i;
                int row = (c << 3) + (l >> 3);
                glds16(gb + (size_t)row * 1024 + ((l & 7) << 4),
                       (char*)&Bs[bufc ^ 1][0] + c * 1024 + l * 16);
            }
            // drain ONLY current buffer's DMAs: 4 A-loads + 8 B-DMAs stay in flight
            asm volatile("s_waitcnt vmcnt(12) lgkmcnt(0)" ::: "memory");
        } else {
            asm volatile("s_waitcnt vmcnt(0) lgkmcnt(0)" ::: "memory");
        }
        __builtin_amdgcn_sched_barrier(0);
        __builtin_amdgcn_s_barrier();
        // MFMA on buffer bufc (swizzled B read: slot = (kc*4+kb) ^ (row&7))
#pragma unroll
        for (int kc = 0; kc < 2; ++kc) {
            short8 afr[4], bfr[4];
#pragma unroll
            for (int mt = 0; mt < 4; ++mt)
                afr[mt] = *(const short8*)&As[mt * 16 + m][kc * 32 + kb * 8];
#pragma unroll
            for (int nt = 0; nt < 4; ++nt) {
                int r = wv * 64 + nt * 16 + m;
                int s = (kc * 4 + kb) ^ (r & 7);
                bfr[nt] = *(const short8*)&Bs[bufc][r * 64 + s * 8];
            }
#pragma unroll
            for (int mt = 0; mt < 4; ++mt)
#pragma unroll
                for (int nt = 0; nt < 4; ++nt)
                    acc[mt][nt] = __builtin_amdgcn_mfma_f32_16x16x32_bf16(
                        afr[mt], bfr[nt], acc[mt][nt], 0, 0, 0);
        }
        asm volatile("" ::: "memory");
        __builtin_amdgcn_s_barrier();
    }

    // ---- epilogue: wave's cols = wv*64 + nt*16 + m ----
    const int rg = kb;
    if (wv < 2) {
        // k half (cols 0..127): per-row dot with u
#pragma unroll
        for (int mt = 0; mt < 4; ++mt) {
            float p[4] = {0.f, 0.f, 0.f, 0.f};
#pragma unroll
            for (int nt = 0; nt < 4; ++nt) {
                int col = wv * 64 + nt * 16 + m;
                float bsv = bias[col], uw = u[col];
#pragma unroll
                for (int j = 0; j < 4; ++j) {
                    float vvv = acc[mt][nt][j] + bsv;
                    vvv = vvv > 0.f ? vvv : 0.f;
                    p[j] += vvv * uw;
                }
            }
#pragma unroll
            for (int j = 0; j < 4; ++j) {
                p[j] += __shfl_xor(p[j], 1);
                p[j] += __shfl_xor(p[j], 2);
                p[j] += __shfl_xor(p[j], 4);
                p[j] += __shfl_xor(p[j], 8);
            }
            if (m == 0) {
#pragma unroll
                for (int j = 0; j < 4; ++j)
                    s_red[mt * 16 + rg * 4 + j][wv] = p[j];
            }
        }
    } else {
        // v half (cols 128..255): bias + relu -> bf16 store
#pragma unroll
        for (int mt = 0; mt < 4; ++mt) {
#pragma unroll
            for (int nt = 0; nt < 4; ++nt) {
                int col = wv * 64 + nt * 16 + m;      // 128..255
                float bsv = bias[col];
#pragma unroll
                for (int j = 0; j < 4; ++j) {
                    int rowl = mt * 16 + rg * 4 + j;
                    float vvv = acc[mt][nt][j] + bsv;
                    vvv = vvv > 0.f ? vvv : 0.f;
                    vbuf[(size_t)(row0 + rowl) * AA_ + (col - 128)] = f2bf(vvv);
                }
            }
        }
    }
    __syncthreads();
    if (t < BM) sout[row0 + t] = s_red[t][0] + s_red[t][1];
}

// ---------------- wsum (softmax fused): 256 blocks = (b, ch of 128 rows)
//   parts[blk][d] = sum_{j in chunk} softmax_j(s) * v[j,d]
__global__ __launch_bounds__(256)
void wsum_kernel(const ushort* __restrict__ vbuf, const float* __restrict__ sg,
                 float* __restrict__ parts) {
    __shared__ float redM[5], redS[5];
    __shared__ float pw[4][128];
    const int blk = blockIdx.x;                 // 0..255
    const int b = blk >> 5, ch = blk & 31;
    const int t = threadIdx.x, wv = t >> 6, l = t & 63;
    const float inv_s = 0.08838834764831843f;   // 1/sqrt(128)

    // softmax stats over batch b (redundant per block; scores are L2-resident)
    float vl[16], mx = -1e30f;
#pragma unroll
    for (int i = 0; i < 16; ++i) {
        vl[i] = sg[b * 4096 + i * 256 + t];
        mx = fmaxf(mx, vl[i]);
    }
#pragma unroll
    for (int off = 1; off < 64; off <<= 1) mx = fmaxf(mx, __shfl_xor(mx, off));
    if (l == 0) redM[wv] = mx;
    __syncthreads();
    if (t == 0) redM[4] = fmaxf(fmaxf(redM[0], redM[1]), fmaxf(redM[2], redM[3]));
    __syncthreads();
    const float M = redM[4];
    float sm = 0.f;
#pragma unroll
    for (int i = 0; i < 16; ++i) sm += __expf((vl[i] - M) * inv_s);
#pragma unroll
    for (int off = 1; off < 64; off <<= 1) sm += __shfl_xor(sm, off);
    if (l == 0) redS[wv] = sm;
    __syncthreads();
    if (t == 0) redS[4] = 1.0f / (redS[0] + redS[1] + redS[2] + redS[3]);
    __syncthreads();
    const float rS = redS[4];

    // weighted sum over this chunk's 128 rows
    const int rg = l >> 4, d8 = (l & 15) * 8;
    const int rbase = b * 4096 + ch * 128;
    float acc[8] = {};
#pragma unroll
    for (int it = 0; it < 8; ++it) {
        int r = rbase + it * 16 + wv * 4 + rg;
        float wj = __expf((sg[r] - M) * inv_s) * rS;
        short8 vvv = *(const short8*)(vbuf + (size_t)r * AA_ + d8);
#pragma unroll
        for (int j = 0; j < 8; ++j)
            acc[j] += wj * bf2f((ushort)vvv[j]);
    }
#pragma unroll
    for (int j = 0; j < 8; ++j) {
        acc[j] += __shfl_xor(acc[j], 16);
        acc[j] += __shfl_xor(acc[j], 32);
    }
    if (l < 16) {
#pragma unroll
        for (int j = 0; j < 8; ++j) pw[wv][d8 + j] = acc[j];
    }
    __syncthreads();
    if (t < 128) parts[blk * 128 + t] = pw[0][t] + pw[1][t] + pw[2][t] + pw[3][t];
}

// ---------------- broadcast: out[b,i,:] = sum_ch parts[b*32+ch][:]
__global__ __launch_bounds__(256)
void bcast_kernel(const float* __restrict__ parts, float4* __restrict__ out) {
    __shared__ float redp[2][128];
    __shared__ float nvf[128];
    const int t = threadIdx.x;
    const int b = blockIdx.x >> 7;               // 1024 blocks, 128 per batch
    const int d = t & 127, h = t >> 7;
    float s = 0.f;
#pragma unroll
    for (int i = 0; i < 16; ++i)
        s += parts[(size_t)(b * 32 + h * 16 + i) * 128 + d];
    redp[h][d] = s;
    __syncthreads();
    if (t < 128) nvf[t] = redp[0][t] + redp[1][t];
    __syncthreads();
    const float4 val = ((const float4*)nvf)[t & 31];
    float4* o4 = out + (size_t)blockIdx.x * 1024;
#pragma unroll
    for (int it = 0; it < 4; ++it)
        o4[it * 256 + t] = val;
}

extern "C" void kernel_launch(void* const* d_in, const int* in_sizes, int n_in,
                              void* d_out, int out_size, void* d_ws, size_t ws_size,
                              hipStream_t stream) {
    const float* enc = (const float*)d_in[0];
    // d_in[1]=decoder, d_in[2]=Wq, d_in[3]=bq, d_in[8]=Pw: provably unused
    // (softmax is shift-invariant in q_term, which is constant per decoder row)
    const float* Wk = (const float*)d_in[4];
    const float* bk = (const float*)d_in[5];
    const float* Wv = (const float*)d_in[6];
    const float* bv = (const float*)d_in[7];
    const float* Pu = (const float*)d_in[9];
    const float* pv = (const float*)d_in[10];

    char* ws = (char*)d_ws;
    ushort* wct   = (ushort*)(ws + WCT_OFF);
    float*  u     = (float*)(ws + U_OFF);
    float*  bias  = (float*)(ws + BIAS_OFF);
    float*  parts = (float*)(ws + PARTS_OFF);
    float*  sg    = (float*)(ws + S_OFF);
    ushort* vbuf  = (ushort*)(ws + VB_OFF);

    prep_kernel<<<128, 256, 0, stream>>>(Wk, bk, Wv, bv, Pu, pv, wct, u, bias);
    gemm_fused<<<NGRID, 256, 0, stream>>>(enc, wct, bias, u, vbuf, sg);
    wsum_kernel<<<256, 256, 0, stream>>>(vbuf, sg, parts);
    bcast_kernel<<<1024, 256, 0, stream>>>(parts, (float4*)d_out);
}